// Round 3
// baseline (1306.312 us; speedup 1.0000x reference)
//
#include <hip/hip_runtime.h>
#include <hip/hip_bf16.h>
#include <math.h>

#define S_LEN 4096
#define HID   2048
#define NHEADS 8
#define NKVH   4
#define HDIM   256
#define FFN    8192
#define WIN    4096
#define QKV_LD 4096   // fused qkv buffer row stride (q:0..2047 | k:2048..3071 | v:3072..4095)
#define KVBLK  32     // flash key-tile size

typedef __bf16 bf16_t;
typedef __bf16 bf16x4 __attribute__((ext_vector_type(4)));
typedef __bf16 bf16x8 __attribute__((ext_vector_type(8)));
typedef float  floatx4 __attribute__((ext_vector_type(4)));

// s_waitcnt simm16 encodings: vmcnt[3:0]@0 hi[5:4]@14, expcnt@4..6, lgkmcnt@8..11
#define WAITCNT_VM0   0x0f70  // vmcnt(0),  lgkm/exp no-wait
#define WAITCNT_VM8   0x0f78  // vmcnt(8),  lgkm/exp no-wait
#define WAITCNT_LGKM0 0xc07f  // lgkmcnt(0), vm/exp no-wait

// ---------------- reduction helpers (256-thread blocks, 4 waves) ----------------
__device__ inline float waveReduceSum(float v) {
#pragma unroll
    for (int o = 32; o > 0; o >>= 1) v += __shfl_xor(v, o);
    return v;
}
__device__ inline float blockReduceSum(float v, float* sh) {
    int tid = threadIdx.x;
    v = waveReduceSum(v);
    if ((tid & 63) == 0) sh[tid >> 6] = v;
    __syncthreads();
    v = sh[0] + sh[1] + sh[2] + sh[3];
    __syncthreads();
    return v;
}

// ---------------- transpose + cast to bf16: in[R][C] (ldin) -> out[C][R] (ldout) ----------------
template <typename T>
__global__ __launch_bounds__(256) void transpose_bf16_kernel(const T* __restrict__ in,
                                                             bf16_t* __restrict__ out,
                                                             int ldin, int ldout) {
    __shared__ float tile[32][33];
    int tx = threadIdx.x & 31;
    int ty = threadIdx.x >> 5;  // 0..7
    int c0 = blockIdx.x * 32;
    int r0 = blockIdx.y * 32;
#pragma unroll
    for (int i = 0; i < 4; ++i)
        tile[ty + i * 8][tx] = (float)in[(long long)(r0 + ty + i * 8) * ldin + c0 + tx];
    __syncthreads();
#pragma unroll
    for (int i = 0; i < 4; ++i)
        out[(long long)(c0 + ty + i * 8) * ldout + r0 + tx] = (bf16_t)tile[tx][ty + i * 8];
}

// ---------------- RMSNorm (fp32 in -> bf16 out), one row per block ----------------
__global__ __launch_bounds__(256) void rmsnorm_kernel(const float* __restrict__ x,
                                                      const float* __restrict__ w,
                                                      bf16_t* __restrict__ out) {
    __shared__ float sh[4];
    int row = blockIdx.x;
    const float* xr = x + (long long)row * HID;
    float v[8];
    float ss = 0.f;
#pragma unroll
    for (int i = 0; i < 8; ++i) {
        v[i] = xr[threadIdx.x + i * 256];
        ss += v[i] * v[i];
    }
    ss = blockReduceSum(ss, sh);
    float sc = rsqrtf(ss * (1.0f / HID) + 1e-6f);
#pragma unroll
    for (int i = 0; i < 8; ++i) {
        int c = threadIdx.x + i * 256;
        out[(long long)row * HID + c] = (bf16_t)(v[i] * sc * w[c]);
    }
}

// ---------------- RoPE in-place on fused qkv [S][4096] ----------------
__global__ __launch_bounds__(256) void rope_kernel(bf16_t* __restrict__ qkv,
                                                   const int* __restrict__ pos_ids) {
    int s = blockIdx.x;
    float p = (float)pos_ids[s];
    for (int t = threadIdx.x; t < (NHEADS + NKVH) * (HDIM / 2); t += 256) {
        int head = t >> 7;        // 0..11 (0..7 = q heads, 8..11 = kv heads)
        int i = t & 127;          // rotary pair index
        float inv = expf(-(2.0f * (float)i / (float)HDIM) * 9.210340371976184f);  // theta^-2i/HD
        float f = p * inv;
        float sn, cs;
        sincosf(f, &sn, &cs);
        int col = (head < NHEADS) ? head * HDIM : HID + (head - NHEADS) * HDIM;
        bf16_t* base = qkv + (long long)s * QKV_LD + col;
        float a = (float)base[i];
        float b = (float)base[i + 128];
        base[i]       = (bf16_t)(a * cs - b * sn);
        base[i + 128] = (bf16_t)(b * cs + a * sn);
    }
}

// ---------------- flash attention v5: 4-way key split, KVBLK=32 ----------------
// Grid: (32 pairs, NHEADS, 4 kquarters) = 1024 blocks, 256 threads = 4 waves.
// Block handles q-tiles {x, 63-x} (64 rows each, wave = 16 queries); the 32-key
// tiles of each q-tile are split 4 ways across blockIdx.z => every block does
// ~32.5 tile iterations (pairing balances). LDS = 37 KiB; launch_bounds(256,3)
// caps VGPR at 170 => 12 waves/CU (vs 8 before): +50% TLP for this
// latency-bound kernel. T14 reg-staged prefetch, defer-max, setprio retained.
// Partials: op0..op3 (op2/3 live in d_out, dead until O-projection).
__global__ __launch_bounds__(256, 3) void flash_attn_kernel(const bf16_t* __restrict__ qkv,
                                                            const bf16_t* __restrict__ vTg,
                                                            bf16_t* __restrict__ op0,
                                                            bf16_t* __restrict__ op1,
                                                            bf16_t* __restrict__ op2,
                                                            bf16_t* __restrict__ op3,
                                                            float* __restrict__ mlb,
                                                            const int* __restrict__ amask) {
    __shared__ bf16_t sK[KVBLK * 256];    // 16 KiB [key][d], chunk-swizzled
    __shared__ bf16_t sV[256 * KVBLK];    // 16 KiB [d][key], chunk-swizzled
    __shared__ bf16_t sPb[4 * 16 * 40];   // 5 KiB per-wave P buffers

    const int h = blockIdx.y;
    const int kh = blockIdx.z;            // 0..3
    const int tid = threadIdx.x;
    const int lane = tid & 63;
    const int w = tid >> 6;
    const int tl = lane & 15;
    const int quad = lane >> 4;

    const bf16_t* Qh = qkv + h * HDIM;                // stride QKV_LD
    const bf16_t* Kh = qkv + HID + (h >> 1) * HDIM;   // stride QKV_LD
    const bf16_t* Vh = vTg + (long long)(h >> 1) * HDIM * S_LEN;
    bf16_t* Op = (kh == 0) ? op0 : (kh == 1) ? op1 : (kh == 2) ? op2 : op3;
    bf16_t* sP = sPb + w * (16 * 40);     // per-wave P buffer [query][key], stride 40

#pragma unroll 1
    for (int half = 0; half < 2; ++half) {
        const int qi = half ? (63 - blockIdx.x) : blockIdx.x;
        const int qr0 = qi * 64;
        const int ntiles = 2 * qi + 2;        // 32-key tiles covering keys [0, qr0+64)
        const int q4 = ntiles >> 2;
        const int r4 = ntiles & 3;
        const int t0 = kh * q4 + ((kh < r4) ? kh : r4);
        const int t1 = t0 + q4 + ((kh < r4) ? 1 : 0);
        const int irow = qr0 + w * 16 + tl;   // this lane's query row

        // Q fragments (B-operand layout: n=tl -> row, k=quad*8+j)
        const bf16_t* qrow = Qh + (long long)irow * QKV_LD;
        bf16x8 qf[8];
#pragma unroll
        for (int ks = 0; ks < 8; ++ks)
            qf[ks] = *(const bf16x8*)(qrow + (ks * 4 + quad) * 8);

        floatx4 oacc[16] = {};
        float m_i = -3e38f, l_i = 0.f;

        // staging registers for one K/V tile (8 x 16B per thread)
        bf16x8 stK[4], stV[4];
        auto load_tile = [&](int kt) {
#pragma unroll
            for (int it = 0; it < 4; ++it) {
                int s = it * 256 + tid;   // 0..1023 16B slots
                {
                    int m = s >> 5, sg = s & 31, g = sg ^ (m & 7);   // 32 rows x 32 chunks
                    stK[it] = *(const bf16x8*)(Kh + (long long)(kt + m) * QKV_LD + g * 8);
                }
                {
                    int m = s >> 2, sg = s & 3, g = sg ^ (m & 3);    // 256 rows x 4 chunks
                    stV[it] = *(const bf16x8*)(Vh + (long long)m * S_LEN + kt + g * 8);
                }
            }
        };

        if (t0 < t1) load_tile(t0 * KVBLK);   // prologue: first tile in flight

#pragma unroll 1
        for (int t = t0; t < t1; ++t) {
            const int kt = t * KVBLK;
            // ---- drain staged regs to LDS (compiler inserts the vmcnt waits) ----
#pragma unroll
            for (int it = 0; it < 4; ++it) {
                int s = it * 256 + tid;
                *(bf16x8*)(sK + s * 8) = stK[it];
                *(bf16x8*)(sV + s * 8) = stV[it];
            }
            __syncthreads();

            // ---- issue next tile's loads; they land during this tile's compute ----
            if (t + 1 < t1) load_tile((t + 1) * KVBLK);
            __builtin_amdgcn_sched_barrier(0);  // keep loads issued before compute

            // ---- S^T = K Q^T : lane holds S[query=tl][key=kt+ni*16+quad*4+r] ----
            floatx4 sacc[2] = {};
            __builtin_amdgcn_s_setprio(1);
#pragma unroll
            for (int ks = 0; ks < 8; ++ks) {
                bf16x8 kf[2];
#pragma unroll
                for (int ni = 0; ni < 2; ++ni) {
                    int row = ni * 16 + tl;
                    int ph = (ks * 4 + quad) ^ (row & 7);
                    kf[ni] = *(const bf16x8*)(sK + row * 256 + ph * 8);
                }
#pragma unroll
                for (int ni = 0; ni < 2; ++ni)
                    sacc[ni] = __builtin_amdgcn_mfma_f32_16x16x32_bf16(kf[ni], qf[ks], sacc[ni], 0, 0, 0);
            }
            __builtin_amdgcn_s_setprio(0);

            // ---- online softmax (per-lane over 8 keys, 2 cross-quad shuffles) ----
            float sv[2][4];
            float mx = -3e38f;
#pragma unroll
            for (int ni = 0; ni < 2; ++ni) {
                int4 am = *(const int4*)(amask + kt + ni * 16 + quad * 4);
#pragma unroll
                for (int r = 0; r < 4; ++r) {
                    int j = kt + ni * 16 + quad * 4 + r;
                    int amr = (r == 0) ? am.x : (r == 1) ? am.y : (r == 2) ? am.z : am.w;
                    bool valid = (j <= irow) && (j > irow - WIN) && (amr > 0);
                    float x = valid ? sacc[ni][r] * 0.0625f : -3e38f;
                    sv[ni][r] = x;
                    mx = fmaxf(mx, x);
                }
            }
            mx = fmaxf(mx, __shfl_xor(mx, 16));
            mx = fmaxf(mx, __shfl_xor(mx, 32));
            // T13 defer-max: keep old running max unless it grew by >8 (wave-uniform)
            bool noresc = __all(mx <= m_i + 8.0f);
            float mnew = noresc ? m_i : fmaxf(m_i, mx);
            float rs = 0.f;
#pragma unroll
            for (int ni = 0; ni < 2; ++ni) {
                bf16x4 pk;
#pragma unroll
                for (int r = 0; r < 4; ++r) {
                    float p = (sv[ni][r] > -1e37f) ? __expf(sv[ni][r] - mnew) : 0.f;
                    rs += p;
                    pk[r] = (bf16_t)p;
                }
                *(bf16x4*)(sP + tl * 40 + ni * 16 + quad * 4) = pk;  // 8B write, keys consecutive
            }
            rs += __shfl_xor(rs, 16);
            rs += __shfl_xor(rs, 32);
            if (noresc) {
                l_i += rs;
            } else {
                float alpha = __expf(m_i - mnew);
                l_i = l_i * alpha + rs;
                m_i = mnew;
                // redistribute alpha to O rows (row query = quad*4+r)
                floatx4 av;
#pragma unroll
                for (int r = 0; r < 4; ++r) av[r] = __shfl(alpha, quad * 4 + r);
#pragma unroll
                for (int dt = 0; dt < 16; ++dt) oacc[dt] *= av;
            }

            // ---- O += P V : A = P (own wave's LDS), B = sV rows ----
            __builtin_amdgcn_s_setprio(1);
            {
                bf16x8 pf = *(const bf16x8*)(sP + tl * 40 + quad * 8);
#pragma unroll
                for (int dt = 0; dt < 16; ++dt) {
                    int d = dt * 16 + tl;
                    int ph = quad ^ (d & 3);
                    bf16x8 vf = *(const bf16x8*)(sV + d * KVBLK + ph * 8);
                    oacc[dt] = __builtin_amdgcn_mfma_f32_16x16x32_bf16(pf, vf, oacc[dt], 0, 0, 0);
                }
            }
            __builtin_amdgcn_s_setprio(0);
            __syncthreads();  // all waves done with sK/sV/sP before next drain
        }

        // ---- epilogue: normalized partial O + (m,l) ----
        floatx4 inv;
#pragma unroll
        for (int r = 0; r < 4; ++r) {
            float lv = __shfl(l_i, quad * 4 + r);
            inv[r] = (lv > 0.f) ? 1.0f / lv : 0.f;
        }
#pragma unroll
        for (int dt = 0; dt < 16; ++dt) {
#pragma unroll
            for (int r = 0; r < 4; ++r) {
                long long row = qr0 + w * 16 + quad * 4 + r;
                Op[row * HID + h * HDIM + dt * 16 + tl] = (bf16_t)(oacc[dt][r] * inv[r]);
            }
        }
        if (quad == 0) {
            long long mi = ((long long)(kh * NHEADS + h) * S_LEN + qr0 + w * 16 + tl) * 2;
            mlb[mi] = m_i;
            mlb[mi + 1] = l_i;
        }
    }
}

// ---------------- combine the four k-quarter partials (in-place over op0) ----------------
__global__ __launch_bounds__(256) void combine_kernel(bf16_t* __restrict__ op0,
                                                      const bf16_t* __restrict__ op1,
                                                      const bf16_t* __restrict__ op2,
                                                      const bf16_t* __restrict__ op3,
                                                      const float* __restrict__ mlb) {
    int h = blockIdx.x;
    int row = blockIdx.y;
    int d = threadIdx.x;
    float m[4], l[4];
#pragma unroll
    for (int k = 0; k < 4; ++k) {
        long long mi = ((long long)(k * NHEADS + h) * S_LEN + row) * 2;
        m[k] = mlb[mi];
        l[k] = mlb[mi + 1];
    }
    float M = fmaxf(fmaxf(m[0], m[1]), fmaxf(m[2], m[3]));
    float wk[4];
    float wsum = 0.f;
#pragma unroll
    for (int k = 0; k < 4; ++k) {
        wk[k] = (l[k] > 0.f) ? l[k] * __expf(m[k] - M) : 0.f;
        wsum += wk[k];
    }
    float inv = 1.0f / wsum;
    long long idx = (long long)row * HID + h * HDIM + d;
    float v = (wk[0] * (float)op0[idx] + wk[1] * (float)op1[idx] +
               wk[2] * (float)op2[idx] + wk[3] * (float)op3[idx]) * inv;
    op0[idx] = (bf16_t)v;
}

// ---------------- MFMA GEMM: C[M,N] = A[M,K] * Bt[N,K]^T ----------------
// 128x128 tile, BK=64, 256 threads (2x2 waves of 64x64), global_load_lds staging.
// 2-phase double-buffered pipeline (T3-minimum): next tile's 8 gload_lds are
// issued BEFORE computing the current tile; a counted s_waitcnt vmcnt(8) (not 0)
// plus raw s_barrier lets those loads stay in flight across the whole compute
// phase. MODE: 0 = store bf16; 1 = fp32 store of resid+acc; 2 = bf16 store of
// gelu(aux)*acc (aux bf16, may alias C).
template <int MODE>
__global__ __launch_bounds__(256) void gemm_kernel(const bf16_t* __restrict__ A, int lda,
                                                   const bf16_t* __restrict__ Bt, int ldb,
                                                   void* __restrict__ Cv, int ldc,
                                                   const void* __restrict__ aux, int K) {
    __shared__ bf16_t smem[2][2 * 128 * 64];   // 64 KiB: [buf][A(128x64) | B(128x64)]

    const int tid = threadIdx.x;
    const int n0 = blockIdx.x * 128;
    const int m0 = blockIdx.y * 128;

    const int lane = tid & 63;
    const int wid = tid >> 6;
    const int wm = (wid >> 1) * 64;
    const int wn = (wid & 1) * 64;
    const int tl = lane & 15;
    const int quad = lane >> 4;

    floatx4 acc[4][4] = {};

    // stage one 128x64 A-tile + 128x64 B-tile into smem[buf] (8 gload_lds/thread)
    auto stage = [&](int buf, int k0) {
        bf16_t* sA = smem[buf];
        bf16_t* sB = smem[buf] + 128 * 64;
#pragma unroll
        for (int it = 0; it < 4; ++it) {
            int s = it * 256 + tid;      // 16B slot index 0..1023
            int m = s >> 3;              // tile row 0..127
            int sg = s & 7;              // stored chunk within row
            int g = sg ^ (m & 7);        // source chunk (XOR swizzle, self-inverse)
            const bf16_t* ga = A + (long long)(m0 + m) * lda + k0 + g * 8;
            __builtin_amdgcn_global_load_lds((const __attribute__((address_space(1))) void*)ga,
                                             (__attribute__((address_space(3))) void*)(sA + s * 8),
                                             16, 0, 0);
            const bf16_t* gb = Bt + (long long)(n0 + m) * ldb + k0 + g * 8;
            __builtin_amdgcn_global_load_lds((const __attribute__((address_space(1))) void*)gb,
                                             (__attribute__((address_space(3))) void*)(sB + s * 8),
                                             16, 0, 0);
        }
    };

    stage(0, 0);
    int cur = 0;

    for (int k0 = 0; k0 < K; k0 += 64) {
        if (k0 + 64 < K) {
            stage(cur ^ 1, k0 + 64);                    // prefetch next tile (stays in flight)
            __builtin_amdgcn_s_waitcnt(WAITCNT_VM8);    // wait only current tile's 8 loads
        } else {
            __builtin_amdgcn_s_waitcnt(WAITCNT_VM0);    // last tile: drain all
        }
        __builtin_amdgcn_s_barrier();                   // raw: no vmcnt(0) drain
        __builtin_amdgcn_sched_barrier(0);              // no hoisting of ds_reads above barrier

        const bf16_t* sA = smem[cur];
        const bf16_t* sB = smem[cur] + 128 * 64;
#pragma unroll
        for (int kk = 0; kk < 2; ++kk) {
            bf16x8 af[4], bfr[4];
#pragma unroll
            for (int mi = 0; mi < 4; ++mi) {
                int m = wm + mi * 16 + tl;
                int sg = (kk * 4 + quad) ^ (m & 7);
                af[mi] = *(const bf16x8*)(sA + m * 64 + sg * 8);
            }
#pragma unroll
            for (int ni = 0; ni < 4; ++ni) {
                int n = wn + ni * 16 + tl;
                int sg = (kk * 4 + quad) ^ (n & 7);
                bfr[ni] = *(const bf16x8*)(sB + n * 64 + sg * 8);
            }
#pragma unroll
            for (int mi = 0; mi < 4; ++mi)
#pragma unroll
                for (int ni = 0; ni < 4; ++ni)
                    acc[mi][ni] = __builtin_amdgcn_mfma_f32_16x16x32_bf16(af[mi], bfr[ni], acc[mi][ni], 0, 0, 0);
        }

        __builtin_amdgcn_s_waitcnt(WAITCNT_LGKM0);      // ds_reads of cur complete
        __builtin_amdgcn_sched_barrier(0);
        __builtin_amdgcn_s_barrier();                   // raw: next stage may overwrite cur
        cur ^= 1;
    }

    // epilogue: C/D layout col=lane&15, row=quad*4+r
#pragma unroll
    for (int mi = 0; mi < 4; ++mi) {
#pragma unroll
        for (int ni = 0; ni < 4; ++ni) {
#pragma unroll
            for (int r = 0; r < 4; ++r) {
                int gr = m0 + wm + mi * 16 + quad * 4 + r;
                int gc = n0 + wn + ni * 16 + tl;
                long long idx = (long long)gr * ldc + gc;
                float v = acc[mi][ni][r];
                if (MODE == 0) {
                    ((bf16_t*)Cv)[idx] = (bf16_t)v;
                } else if (MODE == 1) {
                    ((float*)Cv)[idx] = ((const float*)aux)[idx] + v;
                } else {
                    float g = (float)((const bf16_t*)aux)[idx];
                    float t = 0.7978845608028654f * (g + 0.044715f * g * g * g);
                    float ge = 0.5f * g * (1.0f + tanhf(t));
                    ((bf16_t*)Cv)[idx] = (bf16_t)(ge * v);
                }
            }
        }
    }
}

// ---------------- launch ----------------
extern "C" void kernel_launch(void* const* d_in, const int* in_sizes, int n_in,
                              void* d_out, int out_size, void* d_ws, size_t ws_size,
                              hipStream_t stream) {
    const float* hidden = (const float*)d_in[0];
    const float* q_w    = (const float*)d_in[1];
    const float* k_w    = (const float*)d_in[2];
    const float* v_w    = (const float*)d_in[3];
    const float* o_w    = (const float*)d_in[4];
    const float* gate_w = (const float*)d_in[5];
    const float* up_w   = (const float*)d_in[6];
    const float* down_w = (const float*)d_in[7];
    const float* ln1_w  = (const float*)d_in[8];
    const float* ln2_w  = (const float*)d_in[9];
    const int* amask    = (const int*)d_in[10];
    const int* pos_ids  = (const int*)d_in[11];
    float* out = (float*)d_out;

    // ---- workspace layout (peak 200 MiB) ----
    // 0..16 wqkvT (contiguous q|k|v weight rows) | 16..24 woT | 24..56 wgT |
    // 56..88 wuT | 88..120 wdT | 120..136 xb/op0/attnb/xb2 (time-shared) |
    // 136..168 qkvb (fused) | 168..176 vT | 176..192 op1 | 192..193 ml |
    // 136..200 gateb (after attention dead). op2/op3 live in d_out (32 MiB,
    // dead until the O-projection GEMM which runs after combine).
    const size_t MB = 1ull << 20;
    char* ws = (char*)d_ws;
    bf16_t* wqT = (bf16_t*)(ws + 0 * MB);     // rows 0..2047 of fused wqkvT
    bf16_t* wkT = (bf16_t*)(ws + 8 * MB);     // rows 2048..3071
    bf16_t* wvT = (bf16_t*)(ws + 12 * MB);    // rows 3072..4095
    bf16_t* woT = (bf16_t*)(ws + 16 * MB);
    bf16_t* wgT = (bf16_t*)(ws + 24 * MB);
    bf16_t* wuT = (bf16_t*)(ws + 56 * MB);
    bf16_t* wdT = (bf16_t*)(ws + 88 * MB);
    bf16_t* xb    = (bf16_t*)(ws + 120 * MB);  // rms1 out; later op0/attnb/xb2
    bf16_t* qkvb  = (bf16_t*)(ws + 136 * MB);  // fused [4096][4096]
    bf16_t* vT    = (bf16_t*)(ws + 168 * MB);
    bf16_t* op0   = (bf16_t*)(ws + 120 * MB);  // aliases xb (dead during attention)
    bf16_t* op1   = (bf16_t*)(ws + 176 * MB);
    bf16_t* op2   = (bf16_t*)d_out;            // d_out scratch (16 MiB)
    bf16_t* op3   = (bf16_t*)d_out + (16 * MB / sizeof(bf16_t));
    float*  mlb   = (float*) (ws + 192 * MB);  // 1 MiB (4 splits)
    bf16_t* attnb = (bf16_t*)(ws + 120 * MB);  // combine output, in-place over op0
    bf16_t* xb2   = (bf16_t*)(ws + 120 * MB);  // rms2 out, over dead attnb
    bf16_t* gateb = (bf16_t*)(ws + 136 * MB);  // 64 MiB, over dead attention pool
    (void)ws_size; (void)in_sizes; (void)n_in; (void)out_size;

    dim3 blk(256);

    // weight transpose + bf16 cast: w[K,N] -> wT[N,K]
    transpose_bf16_kernel<float><<<dim3(64, 64), blk, 0, stream>>>(q_w, wqT, 2048, 2048);
    transpose_bf16_kernel<float><<<dim3(32, 64), blk, 0, stream>>>(k_w, wkT, 1024, 2048);
    transpose_bf16_kernel<float><<<dim3(32, 64), blk, 0, stream>>>(v_w, wvT, 1024, 2048);
    transpose_bf16_kernel<float><<<dim3(64, 64), blk, 0, stream>>>(o_w, woT, 2048, 2048);
    transpose_bf16_kernel<float><<<dim3(256, 64), blk, 0, stream>>>(gate_w, wgT, 8192, 2048);
    transpose_bf16_kernel<float><<<dim3(256, 64), blk, 0, stream>>>(up_w, wuT, 8192, 2048);
    transpose_bf16_kernel<float><<<dim3(64, 256), blk, 0, stream>>>(down_w, wdT, 2048, 8192);

    // RMSNorm 1
    rmsnorm_kernel<<<dim3(S_LEN), blk, 0, stream>>>(hidden, ln1_w, xb);

    // fused QKV projection: [4096,2048] x [4096,2048]^T -> qkv [4096][4096]
    gemm_kernel<0><<<dim3(32, 32), blk, 0, stream>>>(xb, HID, wqT, HID, qkvb, QKV_LD, nullptr, HID);

    // RoPE (in-place on fused qkv)
    rope_kernel<<<dim3(S_LEN), blk, 0, stream>>>(qkvb, pos_ids);

    // v^T for flash PV: v region of qkv (cols 3072..4095, stride 4096) -> vT[1024][4096]
    transpose_bf16_kernel<bf16_t><<<dim3(32, 128), blk, 0, stream>>>(qkvb + 3072, vT, QKV_LD, S_LEN);

    // flash attention (4-way key split, paired q-tiles) -> op0..op3 + ml
    flash_attn_kernel<<<dim3(32, NHEADS, 4), blk, 0, stream>>>(qkvb, vT, op0, op1, op2, op3, mlb, amask);
    combine_kernel<<<dim3(NHEADS, S_LEN), blk, 0, stream>>>(op0, op1, op2, op3, mlb);

    // O projection + residual into d_out (fp32)
    gemm_kernel<1><<<dim3(16, 32), blk, 0, stream>>>(attnb, 2048, woT, 2048, out, 2048, hidden, 2048);

    // RMSNorm 2
    rmsnorm_kernel<<<dim3(S_LEN), blk, 0, stream>>>(out, ln2_w, xb2);

    // MLP: gate, up (fused gelu*up in-place), down (+residual into d_out)
    gemm_kernel<0><<<dim3(64, 32), blk, 0, stream>>>(xb2, HID, wgT, HID, gateb, FFN, nullptr, HID);
    gemm_kernel<2><<<dim3(64, 32), blk, 0, stream>>>(xb2, HID, wuT, HID, gateb, FFN, gateb, HID);
    gemm_kernel<1><<<dim3(16, 32), blk, 0, stream>>>(gateb, FFN, wdT, FFN, out, 2048, out, FFN);
}

// Round 4
// 1237.671 us; speedup vs baseline: 1.0555x; 1.0555x over previous
//
#include <hip/hip_runtime.h>
#include <hip/hip_bf16.h>
#include <math.h>

#define S_LEN 4096
#define HID   2048
#define NHEADS 8
#define NKVH   4
#define HDIM   256
#define FFN    8192
#define WIN    4096
#define QKV_LD 4096   // fused qkv buffer row stride (q:0..2047 | k:2048..3071 | v:3072..4095)

typedef __bf16 bf16_t;
typedef __bf16 bf16x4 __attribute__((ext_vector_type(4)));
typedef __bf16 bf16x8 __attribute__((ext_vector_type(8)));
typedef float  floatx4 __attribute__((ext_vector_type(4)));

// s_waitcnt simm16 encodings: vmcnt[3:0]@0 hi[5:4]@14, expcnt@4..6, lgkmcnt@8..11
#define WAITCNT_VM0   0x0f70  // vmcnt(0),  lgkm/exp no-wait
#define WAITCNT_VM4   0x0f74  // vmcnt(4)
#define WAITCNT_VM8   0x0f78  // vmcnt(8)
#define WAITCNT_LGKM0 0xc07f  // lgkmcnt(0), vm/exp no-wait

// ---------------- reduction helpers (256-thread blocks, 4 waves) ----------------
__device__ inline float waveReduceSum(float v) {
#pragma unroll
    for (int o = 32; o > 0; o >>= 1) v += __shfl_xor(v, o);
    return v;
}
__device__ inline float blockReduceSum(float v, float* sh) {
    int tid = threadIdx.x;
    v = waveReduceSum(v);
    if ((tid & 63) == 0) sh[tid >> 6] = v;
    __syncthreads();
    v = sh[0] + sh[1] + sh[2] + sh[3];
    __syncthreads();
    return v;
}

// ---------------- transpose + cast to bf16: in[R][C] (ldin) -> out[C][R] (ldout) ----------------
template <typename T>
__global__ __launch_bounds__(256) void transpose_bf16_kernel(const T* __restrict__ in,
                                                             bf16_t* __restrict__ out,
                                                             int ldin, int ldout) {
    __shared__ float tile[32][33];
    int tx = threadIdx.x & 31;
    int ty = threadIdx.x >> 5;  // 0..7
    int c0 = blockIdx.x * 32;
    int r0 = blockIdx.y * 32;
#pragma unroll
    for (int i = 0; i < 4; ++i)
        tile[ty + i * 8][tx] = (float)in[(long long)(r0 + ty + i * 8) * ldin + c0 + tx];
    __syncthreads();
#pragma unroll
    for (int i = 0; i < 4; ++i)
        out[(long long)(c0 + ty + i * 8) * ldout + r0 + tx] = (bf16_t)tile[tx][ty + i * 8];
}

// ---------------- RMSNorm (fp32 in -> bf16 out), one row per block ----------------
__global__ __launch_bounds__(256) void rmsnorm_kernel(const float* __restrict__ x,
                                                      const float* __restrict__ w,
                                                      bf16_t* __restrict__ out) {
    __shared__ float sh[4];
    int row = blockIdx.x;
    const float* xr = x + (long long)row * HID;
    float v[8];
    float ss = 0.f;
#pragma unroll
    for (int i = 0; i < 8; ++i) {
        v[i] = xr[threadIdx.x + i * 256];
        ss += v[i] * v[i];
    }
    ss = blockReduceSum(ss, sh);
    float sc = rsqrtf(ss * (1.0f / HID) + 1e-6f);
#pragma unroll
    for (int i = 0; i < 8; ++i) {
        int c = threadIdx.x + i * 256;
        out[(long long)row * HID + c] = (bf16_t)(v[i] * sc * w[c]);
    }
}

// ---------------- RoPE in-place on fused qkv [S][4096] ----------------
__global__ __launch_bounds__(256) void rope_kernel(bf16_t* __restrict__ qkv,
                                                   const int* __restrict__ pos_ids) {
    int s = blockIdx.x;
    float p = (float)pos_ids[s];
    for (int t = threadIdx.x; t < (NHEADS + NKVH) * (HDIM / 2); t += 256) {
        int head = t >> 7;        // 0..11 (0..7 = q heads, 8..11 = kv heads)
        int i = t & 127;          // rotary pair index
        float inv = expf(-(2.0f * (float)i / (float)HDIM) * 9.210340371976184f);  // theta^-2i/HD
        float f = p * inv;
        float sn, cs;
        sincosf(f, &sn, &cs);
        int col = (head < NHEADS) ? head * HDIM : HID + (head - NHEADS) * HDIM;
        bf16_t* base = qkv + (long long)s * QKV_LD + col;
        float a = (float)base[i];
        float b = (float)base[i + 128];
        base[i]       = (bf16_t)(a * cs - b * sn);
        base[i + 128] = (bf16_t)(b * cs + a * sn);
    }
}

// ---------------- flash attention (R2 version, known-good 248 us) ----------------
// Grid: (32 pairs, NHEADS, 2 khalves) = 512 blocks, 256 threads = 4 waves.
// KVBLK=64, 74.75 KiB LDS, 2 blocks/CU. T14 reg-staged prefetch, dealiased sP,
// defer-max, setprio. R3's occupancy experiment (launch_bounds cap) spilled to
// scratch (VGPR 84, WRITE_SIZE 33->228 MB) and regressed 1.6x -- reverted.
__global__ __launch_bounds__(256) void flash_attn_kernel(const bf16_t* __restrict__ qkv,
                                                         const bf16_t* __restrict__ vTg,
                                                         bf16_t* __restrict__ op0,
                                                         bf16_t* __restrict__ op1,
                                                         float* __restrict__ mlb,
                                                         const int* __restrict__ amask) {
    __shared__ bf16_t sK[64 * 256];       // 32 KiB [key][d], chunk-swizzled
    __shared__ bf16_t sV[256 * 64];       // 32 KiB [d][key], chunk-swizzled
    __shared__ bf16_t sPb[4 * 16 * 72];   // 9 KiB per-wave P buffers (no alias)

    const int h = blockIdx.y;
    const int kh = blockIdx.z;
    const int tid = threadIdx.x;
    const int lane = tid & 63;
    const int w = tid >> 6;
    const int tl = lane & 15;
    const int quad = lane >> 4;

    const bf16_t* Qh = qkv + h * HDIM;                // stride QKV_LD
    const bf16_t* Kh = qkv + HID + (h >> 1) * HDIM;   // stride QKV_LD
    const bf16_t* Vh = vTg + (long long)(h >> 1) * HDIM * S_LEN;
    bf16_t* Op = kh ? op1 : op0;
    bf16_t* sP = sPb + w * (16 * 72);     // per-wave P buffer [query][key], stride 72

#pragma unroll 1
    for (int half = 0; half < 2; ++half) {
        const int qi = half ? (63 - blockIdx.x) : blockIdx.x;
        const int qr0 = qi * 64;
        const int ntiles = qi + 1;
        const int mid = ntiles >> 1;
        const int t0 = kh ? mid : 0;
        const int t1 = kh ? ntiles : mid;
        const int irow = qr0 + w * 16 + tl;   // this lane's query row

        // Q fragments (B-operand layout: n=tl -> row, k=quad*8+j)
        const bf16_t* qrow = Qh + (long long)irow * QKV_LD;
        bf16x8 qf[8];
#pragma unroll
        for (int ks = 0; ks < 8; ++ks)
            qf[ks] = *(const bf16x8*)(qrow + (ks * 4 + quad) * 8);

        floatx4 oacc[16] = {};
        float m_i = -3e38f, l_i = 0.f;

        // staging registers for one K/V tile (16 x 16B per thread)
        bf16x8 stK[8], stV[8];
        auto load_tile = [&](int kt) {
#pragma unroll
            for (int it = 0; it < 8; ++it) {
                int s = it * 256 + tid;
                {
                    int m = s >> 5, sg = s & 31, g = sg ^ (m & 7);
                    stK[it] = *(const bf16x8*)(Kh + (long long)(kt + m) * QKV_LD + g * 8);
                }
                {
                    int m = s >> 3, sg = s & 7, g = sg ^ (m & 7);
                    stV[it] = *(const bf16x8*)(Vh + (long long)m * S_LEN + kt + g * 8);
                }
            }
        };

        if (t0 < t1) load_tile(t0 * 64);   // prologue: first tile in flight

#pragma unroll 1
        for (int t = t0; t < t1; ++t) {
            const int kt = t * 64;
            // ---- drain staged regs to LDS (compiler inserts the vmcnt waits) ----
#pragma unroll
            for (int it = 0; it < 8; ++it) {
                int s = it * 256 + tid;
                *(bf16x8*)(sK + s * 8) = stK[it];
                *(bf16x8*)(sV + s * 8) = stV[it];
            }
            __syncthreads();

            // ---- issue next tile's loads; they land during this tile's compute ----
            if (t + 1 < t1) load_tile((t + 1) * 64);
            __builtin_amdgcn_sched_barrier(0);  // keep loads issued before compute

            // ---- S^T = K Q^T : lane holds S[query=tl][key=kt+ni*16+quad*4+r] ----
            floatx4 sacc[4] = {};
            __builtin_amdgcn_s_setprio(1);
#pragma unroll
            for (int ks = 0; ks < 8; ++ks) {
                bf16x8 kf[4];
#pragma unroll
                for (int ni = 0; ni < 4; ++ni) {
                    int row = ni * 16 + tl;
                    int ph = (ks * 4 + quad) ^ (row & 7);
                    kf[ni] = *(const bf16x8*)(sK + row * 256 + ph * 8);
                }
#pragma unroll
                for (int ni = 0; ni < 4; ++ni)
                    sacc[ni] = __builtin_amdgcn_mfma_f32_16x16x32_bf16(kf[ni], qf[ks], sacc[ni], 0, 0, 0);
            }
            __builtin_amdgcn_s_setprio(0);

            // ---- online softmax (per-lane over 16 keys, 2 cross-quad shuffles) ----
            float sv[4][4];
            float mx = -3e38f;
#pragma unroll
            for (int ni = 0; ni < 4; ++ni) {
                int4 am = *(const int4*)(amask + kt + ni * 16 + quad * 4);
#pragma unroll
                for (int r = 0; r < 4; ++r) {
                    int j = kt + ni * 16 + quad * 4 + r;
                    int amr = (r == 0) ? am.x : (r == 1) ? am.y : (r == 2) ? am.z : am.w;
                    bool valid = (j <= irow) && (j > irow - WIN) && (amr > 0);
                    float x = valid ? sacc[ni][r] * 0.0625f : -3e38f;
                    sv[ni][r] = x;
                    mx = fmaxf(mx, x);
                }
            }
            mx = fmaxf(mx, __shfl_xor(mx, 16));
            mx = fmaxf(mx, __shfl_xor(mx, 32));
            // T13 defer-max: keep old running max unless it grew by >8 (wave-uniform)
            bool noresc = __all(mx <= m_i + 8.0f);
            float mnew = noresc ? m_i : fmaxf(m_i, mx);
            float rs = 0.f;
#pragma unroll
            for (int ni = 0; ni < 4; ++ni) {
                bf16x4 pk;
#pragma unroll
                for (int r = 0; r < 4; ++r) {
                    float p = (sv[ni][r] > -1e37f) ? __expf(sv[ni][r] - mnew) : 0.f;
                    rs += p;
                    pk[r] = (bf16_t)p;
                }
                *(bf16x4*)(sP + tl * 72 + ni * 16 + quad * 4) = pk;  // 8B write, keys consecutive
            }
            rs += __shfl_xor(rs, 16);
            rs += __shfl_xor(rs, 32);
            if (noresc) {
                l_i += rs;
            } else {
                float alpha = __expf(m_i - mnew);
                l_i = l_i * alpha + rs;
                m_i = mnew;
                // redistribute alpha to O rows (row query = quad*4+r)
                floatx4 av;
#pragma unroll
                for (int r = 0; r < 4; ++r) av[r] = __shfl(alpha, quad * 4 + r);
#pragma unroll
                for (int dt = 0; dt < 16; ++dt) oacc[dt] *= av;
            }

            // ---- O += P V : A = P (own wave's LDS), B = sV rows ----
            __builtin_amdgcn_s_setprio(1);
#pragma unroll
            for (int k2 = 0; k2 < 2; ++k2) {
                bf16x8 pf = *(const bf16x8*)(sP + tl * 72 + k2 * 32 + quad * 8);
#pragma unroll
                for (int dt = 0; dt < 16; ++dt) {
                    int d = dt * 16 + tl;
                    int ph = (k2 * 4 + quad) ^ (d & 7);
                    bf16x8 vf = *(const bf16x8*)(sV + d * 64 + ph * 8);
                    oacc[dt] = __builtin_amdgcn_mfma_f32_16x16x32_bf16(pf, vf, oacc[dt], 0, 0, 0);
                }
            }
            __builtin_amdgcn_s_setprio(0);
            __syncthreads();  // all waves done with sK/sV/sP before next drain
        }

        // ---- epilogue: normalized partial O + (m,l) ----
        floatx4 inv;
#pragma unroll
        for (int r = 0; r < 4; ++r) {
            float lv = __shfl(l_i, quad * 4 + r);
            inv[r] = (lv > 0.f) ? 1.0f / lv : 0.f;
        }
#pragma unroll
        for (int dt = 0; dt < 16; ++dt) {
#pragma unroll
            for (int r = 0; r < 4; ++r) {
                long long row = qr0 + w * 16 + quad * 4 + r;
                Op[row * HID + h * HDIM + dt * 16 + tl] = (bf16_t)(oacc[dt][r] * inv[r]);
            }
        }
        if (quad == 0) {
            long long mi = ((long long)(kh * NHEADS + h) * S_LEN + qr0 + w * 16 + tl) * 2;
            mlb[mi] = m_i;
            mlb[mi + 1] = l_i;
        }
    }
}

// ---------------- combine the two k-half partials (in-place over op0) ----------------
__global__ __launch_bounds__(256) void combine_kernel(bf16_t* __restrict__ op0,
                                                      const bf16_t* __restrict__ op1,
                                                      const float* __restrict__ mlb) {
    int h = blockIdx.x;
    int row = blockIdx.y;
    int d = threadIdx.x;
    long long m0i = ((long long)h * S_LEN + row) * 2;
    long long m1i = ((long long)(NHEADS + h) * S_LEN + row) * 2;
    float m0 = mlb[m0i], l0 = mlb[m0i + 1];
    float m1 = mlb[m1i], l1 = mlb[m1i + 1];
    float M = fmaxf(m0, m1);
    float w0 = (l0 > 0.f) ? l0 * __expf(m0 - M) : 0.f;
    float w1 = (l1 > 0.f) ? l1 * __expf(m1 - M) : 0.f;
    float inv = 1.0f / (w0 + w1);
    long long idx = (long long)row * HID + h * HDIM + d;
    float v = (w0 * (float)op0[idx] + w1 * (float)op1[idx]) * inv;
    op0[idx] = (bf16_t)v;
}

// ---------------- MFMA GEMM: C[M,N] = A[M,K] * Bt[N,K]^T ----------------
// 128x128 tile, BK=32, 256 threads (2x2 waves of 64x64), global_load_lds staging.
// Distance-2 pipeline (T4 deepened): 4 cyclic LDS buffers of 16 KiB (64 KiB total,
// 2 blocks/CU). While computing tile t, tiles t+1 AND t+2 are in flight; the
// per-iteration s_waitcnt vmcnt(8) only requires loads issued TWO compute phases
// ago (~600+ cy) -- covers L3/HBM latency, removing the per-K-step stall that
// distance-1 left. Buffer t+2 overwrites the buffer last read at t-2 (drained by
// that iteration's lgkmcnt(0)+barrier before this stage is issued): race-free.
// Per-K-step accumulate order (k ascending, 32/mfma) identical to BK=64 version
// => bit-identical results. MODE: 0 = store bf16; 1 = fp32 store of resid+acc;
// 2 = bf16 store of gelu(aux)*acc (aux bf16, may alias C).
template <int MODE>
__global__ __launch_bounds__(256) void gemm_kernel(const bf16_t* __restrict__ A, int lda,
                                                   const bf16_t* __restrict__ Bt, int ldb,
                                                   void* __restrict__ Cv, int ldc,
                                                   const void* __restrict__ aux, int K) {
    __shared__ bf16_t smem[4][2 * 128 * 32];   // 4 bufs x 16 KiB: [buf][A(128x32) | B(128x32)]

    const int tid = threadIdx.x;
    const int n0 = blockIdx.x * 128;
    const int m0 = blockIdx.y * 128;

    const int lane = tid & 63;
    const int wid = tid >> 6;
    const int wm = (wid >> 1) * 64;
    const int wn = (wid & 1) * 64;
    const int tl = lane & 15;
    const int quad = lane >> 4;

    floatx4 acc[4][4] = {};

    // stage one 128x32 A-tile + 128x32 B-tile into smem[buf] (4 gload_lds/thread)
    // row = 64 B = 4 chunks of 16 B; XOR swizzle g = sg ^ (m&3). Read pattern
    // chunk quad^(m&3) maps 16 lanes onto 8 distinct 16B granules (2-way, free).
    auto stage = [&](int buf, int k0) {
        bf16_t* sA = smem[buf];
        bf16_t* sB = smem[buf] + 128 * 32;
#pragma unroll
        for (int it = 0; it < 2; ++it) {
            int s = it * 256 + tid;      // 16B slot index 0..511
            int m = s >> 2;              // tile row 0..127
            int sg = s & 3;              // stored chunk within row
            int g = sg ^ (m & 3);        // source chunk (XOR swizzle, self-inverse)
            const bf16_t* ga = A + (long long)(m0 + m) * lda + k0 + g * 8;
            __builtin_amdgcn_global_load_lds((const __attribute__((address_space(1))) void*)ga,
                                             (__attribute__((address_space(3))) void*)(sA + s * 8),
                                             16, 0, 0);
            const bf16_t* gb = Bt + (long long)(n0 + m) * ldb + k0 + g * 8;
            __builtin_amdgcn_global_load_lds((const __attribute__((address_space(1))) void*)gb,
                                             (__attribute__((address_space(3))) void*)(sB + s * 8),
                                             16, 0, 0);
        }
    };

    const int nk = K >> 5;               // K / 32, >= 64 for all our shapes
    stage(0, 0);
    stage(1, 32);

    for (int t = 0; t < nk; ++t) {
        if (t + 2 < nk) {
            stage((t + 2) & 3, (t + 2) * 32);           // keep 2 tiles in flight
            __builtin_amdgcn_s_waitcnt(WAITCNT_VM8);    // force tile t's 4 loads done
        } else if (t + 2 == nk) {
            __builtin_amdgcn_s_waitcnt(WAITCNT_VM4);    // only t+1 (4 loads) may remain
        } else {
            __builtin_amdgcn_s_waitcnt(WAITCNT_VM0);    // last tile: drain
        }
        __builtin_amdgcn_s_barrier();                   // raw: prefetch stays in flight
        __builtin_amdgcn_sched_barrier(0);              // no hoisting above barrier

        const bf16_t* sA = smem[t & 3];
        const bf16_t* sB = smem[t & 3] + 128 * 32;
        bf16x8 af[4], bfr[4];
#pragma unroll
        for (int mi = 0; mi < 4; ++mi) {
            int m = wm + mi * 16 + tl;
            int sg = quad ^ (m & 3);
            af[mi] = *(const bf16x8*)(sA + m * 32 + sg * 8);
        }
#pragma unroll
        for (int ni = 0; ni < 4; ++ni) {
            int n = wn + ni * 16 + tl;
            int sg = quad ^ (n & 3);
            bfr[ni] = *(const bf16x8*)(sB + n * 32 + sg * 8);
        }
        __builtin_amdgcn_s_setprio(1);
#pragma unroll
        for (int mi = 0; mi < 4; ++mi)
#pragma unroll
            for (int ni = 0; ni < 4; ++ni)
                acc[mi][ni] = __builtin_amdgcn_mfma_f32_16x16x32_bf16(af[mi], bfr[ni], acc[mi][ni], 0, 0, 0);
        __builtin_amdgcn_s_setprio(0);

        __builtin_amdgcn_s_waitcnt(WAITCNT_LGKM0);      // this tile's ds_reads complete
        __builtin_amdgcn_sched_barrier(0);
        __builtin_amdgcn_s_barrier();                   // raw: buffer may be overwritten at t+2
    }

    // epilogue: C/D layout col=lane&15, row=quad*4+r
#pragma unroll
    for (int mi = 0; mi < 4; ++mi) {
#pragma unroll
        for (int ni = 0; ni < 4; ++ni) {
#pragma unroll
            for (int r = 0; r < 4; ++r) {
                int gr = m0 + wm + mi * 16 + quad * 4 + r;
                int gc = n0 + wn + ni * 16 + tl;
                long long idx = (long long)gr * ldc + gc;
                float v = acc[mi][ni][r];
                if (MODE == 0) {
                    ((bf16_t*)Cv)[idx] = (bf16_t)v;
                } else if (MODE == 1) {
                    ((float*)Cv)[idx] = ((const float*)aux)[idx] + v;
                } else {
                    float g = (float)((const bf16_t*)aux)[idx];
                    float t = 0.7978845608028654f * (g + 0.044715f * g * g * g);
                    float ge = 0.5f * g * (1.0f + tanhf(t));
                    ((bf16_t*)Cv)[idx] = (bf16_t)(ge * v);
                }
            }
        }
    }
}

// ---------------- launch ----------------
extern "C" void kernel_launch(void* const* d_in, const int* in_sizes, int n_in,
                              void* d_out, int out_size, void* d_ws, size_t ws_size,
                              hipStream_t stream) {
    const float* hidden = (const float*)d_in[0];
    const float* q_w    = (const float*)d_in[1];
    const float* k_w    = (const float*)d_in[2];
    const float* v_w    = (const float*)d_in[3];
    const float* o_w    = (const float*)d_in[4];
    const float* gate_w = (const float*)d_in[5];
    const float* up_w   = (const float*)d_in[6];
    const float* down_w = (const float*)d_in[7];
    const float* ln1_w  = (const float*)d_in[8];
    const float* ln2_w  = (const float*)d_in[9];
    const int* amask    = (const int*)d_in[10];
    const int* pos_ids  = (const int*)d_in[11];
    float* out = (float*)d_out;

    // ---- workspace layout (peak 200 MiB) ----
    // 0..16 wqkvT (contiguous q|k|v weight rows) | 16..24 woT | 24..56 wgT |
    // 56..88 wuT | 88..120 wdT | 120..136 xb/op0/attnb/xb2 (time-shared) |
    // 136..168 qkvb (fused) | 168..176 vT | 176..192 op1 | 192..192.5 ml |
    // 136..200 gateb (after attention dead)
    const size_t MB = 1ull << 20;
    char* ws = (char*)d_ws;
    bf16_t* wqT = (bf16_t*)(ws + 0 * MB);     // rows 0..2047 of fused wqkvT
    bf16_t* wkT = (bf16_t*)(ws + 8 * MB);     // rows 2048..3071
    bf16_t* wvT = (bf16_t*)(ws + 12 * MB);    // rows 3072..4095
    bf16_t* woT = (bf16_t*)(ws + 16 * MB);
    bf16_t* wgT = (bf16_t*)(ws + 24 * MB);
    bf16_t* wuT = (bf16_t*)(ws + 56 * MB);
    bf16_t* wdT = (bf16_t*)(ws + 88 * MB);
    bf16_t* xb    = (bf16_t*)(ws + 120 * MB);  // rms1 out; later op0/attnb/xb2
    bf16_t* qkvb  = (bf16_t*)(ws + 136 * MB);  // fused [4096][4096]
    bf16_t* vT    = (bf16_t*)(ws + 168 * MB);
    bf16_t* op0   = (bf16_t*)(ws + 120 * MB);  // aliases xb (dead during attention)
    bf16_t* op1   = (bf16_t*)(ws + 176 * MB);
    float*  mlb   = (float*) (ws + 192 * MB);
    bf16_t* attnb = (bf16_t*)(ws + 120 * MB);  // combine output, in-place over op0
    bf16_t* xb2   = (bf16_t*)(ws + 120 * MB);  // rms2 out, over dead attnb
    bf16_t* gateb = (bf16_t*)(ws + 136 * MB);  // 64 MiB, over dead attention pool
    (void)ws_size; (void)in_sizes; (void)n_in; (void)out_size;

    dim3 blk(256);

    // weight transpose + bf16 cast: w[K,N] -> wT[N,K]
    transpose_bf16_kernel<float><<<dim3(64, 64), blk, 0, stream>>>(q_w, wqT, 2048, 2048);
    transpose_bf16_kernel<float><<<dim3(32, 64), blk, 0, stream>>>(k_w, wkT, 1024, 2048);
    transpose_bf16_kernel<float><<<dim3(32, 64), blk, 0, stream>>>(v_w, wvT, 1024, 2048);
    transpose_bf16_kernel<float><<<dim3(64, 64), blk, 0, stream>>>(o_w, woT, 2048, 2048);
    transpose_bf16_kernel<float><<<dim3(256, 64), blk, 0, stream>>>(gate_w, wgT, 8192, 2048);
    transpose_bf16_kernel<float><<<dim3(256, 64), blk, 0, stream>>>(up_w, wuT, 8192, 2048);
    transpose_bf16_kernel<float><<<dim3(64, 256), blk, 0, stream>>>(down_w, wdT, 2048, 8192);

    // RMSNorm 1
    rmsnorm_kernel<<<dim3(S_LEN), blk, 0, stream>>>(hidden, ln1_w, xb);

    // fused QKV projection: [4096,2048] x [4096,2048]^T -> qkv [4096][4096]
    gemm_kernel<0><<<dim3(32, 32), blk, 0, stream>>>(xb, HID, wqT, HID, qkvb, QKV_LD, nullptr, HID);

    // RoPE (in-place on fused qkv)
    rope_kernel<<<dim3(S_LEN), blk, 0, stream>>>(qkvb, pos_ids);

    // v^T for flash PV: v region of qkv (cols 3072..4095, stride 4096) -> vT[1024][4096]
    transpose_bf16_kernel<bf16_t><<<dim3(32, 128), blk, 0, stream>>>(qkvb + 3072, vT, QKV_LD, S_LEN);

    // flash attention (split-K halves, paired q-tiles) -> op0/op1 + ml
    flash_attn_kernel<<<dim3(32, NHEADS, 2), blk, 0, stream>>>(qkvb, vT, op0, op1, mlb, amask);
    combine_kernel<<<dim3(NHEADS, S_LEN), blk, 0, stream>>>(op0, op1, mlb);

    // O projection + residual into d_out (fp32)
    gemm_kernel<1><<<dim3(16, 32), blk, 0, stream>>>(attnb, 2048, woT, 2048, out, 2048, hidden, 2048);

    // RMSNorm 2
    rmsnorm_kernel<<<dim3(S_LEN), blk, 0, stream>>>(out, ln2_w, xb2);

    // MLP: gate, up (fused gelu*up in-place), down (+residual into d_out)
    gemm_kernel<0><<<dim3(64, 32), blk, 0, stream>>>(xb2, HID, wgT, HID, gateb, FFN, nullptr, HID);
    gemm_kernel<2><<<dim3(64, 32), blk, 0, stream>>>(xb2, HID, wuT, HID, gateb, FFN, gateb, HID);
    gemm_kernel<1><<<dim3(16, 32), blk, 0, stream>>>(gateb, FFN, wdT, FFN, out, 2048, out, FFN);
}

// Round 5
// 1135.173 us; speedup vs baseline: 1.1508x; 1.0903x over previous
//
#include <hip/hip_runtime.h>
#include <hip/hip_bf16.h>
#include <math.h>

#define S_LEN 4096
#define HID   2048
#define NHEADS 8
#define NKVH   4
#define HDIM   256
#define FFN    8192
#define WIN    4096
#define QKV_LD 4096   // fused qkv buffer row stride (q:0..2047 | k:2048..3071 | v:3072..4095)

typedef __bf16 bf16_t;
typedef __bf16 bf16x4 __attribute__((ext_vector_type(4)));
typedef __bf16 bf16x8 __attribute__((ext_vector_type(8)));
typedef float  floatx4 __attribute__((ext_vector_type(4)));

// s_waitcnt simm16 encodings: vmcnt[3:0]@0 hi[5:4]@14, expcnt@4..6, lgkmcnt@8..11
#define WAITCNT_VM0   0x0f70  // vmcnt(0),  lgkm/exp no-wait
#define WAITCNT_VM8   0x0f78  // vmcnt(8)
#define WAITCNT_LGKM0 0xc07f  // lgkmcnt(0), vm/exp no-wait

// ---------------- reduction helpers (256-thread blocks, 4 waves) ----------------
__device__ inline float waveReduceSum(float v) {
#pragma unroll
    for (int o = 32; o > 0; o >>= 1) v += __shfl_xor(v, o);
    return v;
}
__device__ inline float blockReduceSum(float v, float* sh) {
    int tid = threadIdx.x;
    v = waveReduceSum(v);
    if ((tid & 63) == 0) sh[tid >> 6] = v;
    __syncthreads();
    v = sh[0] + sh[1] + sh[2] + sh[3];
    __syncthreads();
    return v;
}

// ---------------- transpose + cast to bf16: in[R][C] (ldin) -> out[C][R] (ldout) ----------------
template <typename T>
__global__ __launch_bounds__(256) void transpose_bf16_kernel(const T* __restrict__ in,
                                                             bf16_t* __restrict__ out,
                                                             int ldin, int ldout) {
    __shared__ float tile[32][33];
    int tx = threadIdx.x & 31;
    int ty = threadIdx.x >> 5;  // 0..7
    int c0 = blockIdx.x * 32;
    int r0 = blockIdx.y * 32;
#pragma unroll
    for (int i = 0; i < 4; ++i)
        tile[ty + i * 8][tx] = (float)in[(long long)(r0 + ty + i * 8) * ldin + c0 + tx];
    __syncthreads();
#pragma unroll
    for (int i = 0; i < 4; ++i)
        out[(long long)(c0 + ty + i * 8) * ldout + r0 + tx] = (bf16_t)tile[tx][ty + i * 8];
}

// ---------------- RMSNorm (fp32 in -> bf16 out), one row per block ----------------
__global__ __launch_bounds__(256) void rmsnorm_kernel(const float* __restrict__ x,
                                                      const float* __restrict__ w,
                                                      bf16_t* __restrict__ out) {
    __shared__ float sh[4];
    int row = blockIdx.x;
    const float* xr = x + (long long)row * HID;
    float v[8];
    float ss = 0.f;
#pragma unroll
    for (int i = 0; i < 8; ++i) {
        v[i] = xr[threadIdx.x + i * 256];
        ss += v[i] * v[i];
    }
    ss = blockReduceSum(ss, sh);
    float sc = rsqrtf(ss * (1.0f / HID) + 1e-6f);
#pragma unroll
    for (int i = 0; i < 8; ++i) {
        int c = threadIdx.x + i * 256;
        out[(long long)row * HID + c] = (bf16_t)(v[i] * sc * w[c]);
    }
}

// ---------------- RoPE in-place on fused qkv [S][4096] ----------------
__global__ __launch_bounds__(256) void rope_kernel(bf16_t* __restrict__ qkv,
                                                   const int* __restrict__ pos_ids) {
    int s = blockIdx.x;
    float p = (float)pos_ids[s];
    for (int t = threadIdx.x; t < (NHEADS + NKVH) * (HDIM / 2); t += 256) {
        int head = t >> 7;        // 0..11 (0..7 = q heads, 8..11 = kv heads)
        int i = t & 127;          // rotary pair index
        float inv = expf(-(2.0f * (float)i / (float)HDIM) * 9.210340371976184f);  // theta^-2i/HD
        float f = p * inv;
        float sn, cs;
        sincosf(f, &sn, &cs);
        int col = (head < NHEADS) ? head * HDIM : HID + (head - NHEADS) * HDIM;
        bf16_t* base = qkv + (long long)s * QKV_LD + col;
        float a = (float)base[i];
        float b = (float)base[i + 128];
        base[i]       = (bf16_t)(a * cs - b * sn);
        base[i + 128] = (bf16_t)(b * cs + a * sn);
    }
}

// ---------------- flash attention (R2 version, known-good 248 us) ----------------
__global__ __launch_bounds__(256) void flash_attn_kernel(const bf16_t* __restrict__ qkv,
                                                         const bf16_t* __restrict__ vTg,
                                                         bf16_t* __restrict__ op0,
                                                         bf16_t* __restrict__ op1,
                                                         float* __restrict__ mlb,
                                                         const int* __restrict__ amask) {
    __shared__ bf16_t sK[64 * 256];       // 32 KiB [key][d], chunk-swizzled
    __shared__ bf16_t sV[256 * 64];       // 32 KiB [d][key], chunk-swizzled
    __shared__ bf16_t sPb[4 * 16 * 72];   // 9 KiB per-wave P buffers (no alias)

    const int h = blockIdx.y;
    const int kh = blockIdx.z;
    const int tid = threadIdx.x;
    const int lane = tid & 63;
    const int w = tid >> 6;
    const int tl = lane & 15;
    const int quad = lane >> 4;

    const bf16_t* Qh = qkv + h * HDIM;                // stride QKV_LD
    const bf16_t* Kh = qkv + HID + (h >> 1) * HDIM;   // stride QKV_LD
    const bf16_t* Vh = vTg + (long long)(h >> 1) * HDIM * S_LEN;
    bf16_t* Op = kh ? op1 : op0;
    bf16_t* sP = sPb + w * (16 * 72);     // per-wave P buffer [query][key], stride 72

#pragma unroll 1
    for (int half = 0; half < 2; ++half) {
        const int qi = half ? (63 - blockIdx.x) : blockIdx.x;
        const int qr0 = qi * 64;
        const int ntiles = qi + 1;
        const int mid = ntiles >> 1;
        const int t0 = kh ? mid : 0;
        const int t1 = kh ? ntiles : mid;
        const int irow = qr0 + w * 16 + tl;   // this lane's query row

        // Q fragments (B-operand layout: n=tl -> row, k=quad*8+j)
        const bf16_t* qrow = Qh + (long long)irow * QKV_LD;
        bf16x8 qf[8];
#pragma unroll
        for (int ks = 0; ks < 8; ++ks)
            qf[ks] = *(const bf16x8*)(qrow + (ks * 4 + quad) * 8);

        floatx4 oacc[16] = {};
        float m_i = -3e38f, l_i = 0.f;

        // staging registers for one K/V tile (16 x 16B per thread)
        bf16x8 stK[8], stV[8];
        auto load_tile = [&](int kt) {
#pragma unroll
            for (int it = 0; it < 8; ++it) {
                int s = it * 256 + tid;
                {
                    int m = s >> 5, sg = s & 31, g = sg ^ (m & 7);
                    stK[it] = *(const bf16x8*)(Kh + (long long)(kt + m) * QKV_LD + g * 8);
                }
                {
                    int m = s >> 3, sg = s & 7, g = sg ^ (m & 7);
                    stV[it] = *(const bf16x8*)(Vh + (long long)m * S_LEN + kt + g * 8);
                }
            }
        };

        if (t0 < t1) load_tile(t0 * 64);   // prologue: first tile in flight

#pragma unroll 1
        for (int t = t0; t < t1; ++t) {
            const int kt = t * 64;
            // ---- drain staged regs to LDS (compiler inserts the vmcnt waits) ----
#pragma unroll
            for (int it = 0; it < 8; ++it) {
                int s = it * 256 + tid;
                *(bf16x8*)(sK + s * 8) = stK[it];
                *(bf16x8*)(sV + s * 8) = stV[it];
            }
            __syncthreads();

            // ---- issue next tile's loads; they land during this tile's compute ----
            if (t + 1 < t1) load_tile((t + 1) * 64);
            __builtin_amdgcn_sched_barrier(0);  // keep loads issued before compute

            // ---- S^T = K Q^T : lane holds S[query=tl][key=kt+ni*16+quad*4+r] ----
            floatx4 sacc[4] = {};
            __builtin_amdgcn_s_setprio(1);
#pragma unroll
            for (int ks = 0; ks < 8; ++ks) {
                bf16x8 kf[4];
#pragma unroll
                for (int ni = 0; ni < 4; ++ni) {
                    int row = ni * 16 + tl;
                    int ph = (ks * 4 + quad) ^ (row & 7);
                    kf[ni] = *(const bf16x8*)(sK + row * 256 + ph * 8);
                }
#pragma unroll
                for (int ni = 0; ni < 4; ++ni)
                    sacc[ni] = __builtin_amdgcn_mfma_f32_16x16x32_bf16(kf[ni], qf[ks], sacc[ni], 0, 0, 0);
            }
            __builtin_amdgcn_s_setprio(0);

            // ---- online softmax (per-lane over 16 keys, 2 cross-quad shuffles) ----
            float sv[4][4];
            float mx = -3e38f;
#pragma unroll
            for (int ni = 0; ni < 4; ++ni) {
                int4 am = *(const int4*)(amask + kt + ni * 16 + quad * 4);
#pragma unroll
                for (int r = 0; r < 4; ++r) {
                    int j = kt + ni * 16 + quad * 4 + r;
                    int amr = (r == 0) ? am.x : (r == 1) ? am.y : (r == 2) ? am.z : am.w;
                    bool valid = (j <= irow) && (j > irow - WIN) && (amr > 0);
                    float x = valid ? sacc[ni][r] * 0.0625f : -3e38f;
                    sv[ni][r] = x;
                    mx = fmaxf(mx, x);
                }
            }
            mx = fmaxf(mx, __shfl_xor(mx, 16));
            mx = fmaxf(mx, __shfl_xor(mx, 32));
            // T13 defer-max: keep old running max unless it grew by >8 (wave-uniform)
            bool noresc = __all(mx <= m_i + 8.0f);
            float mnew = noresc ? m_i : fmaxf(m_i, mx);
            float rs = 0.f;
#pragma unroll
            for (int ni = 0; ni < 4; ++ni) {
                bf16x4 pk;
#pragma unroll
                for (int r = 0; r < 4; ++r) {
                    float p = (sv[ni][r] > -1e37f) ? __expf(sv[ni][r] - mnew) : 0.f;
                    rs += p;
                    pk[r] = (bf16_t)p;
                }
                *(bf16x4*)(sP + tl * 72 + ni * 16 + quad * 4) = pk;  // 8B write, keys consecutive
            }
            rs += __shfl_xor(rs, 16);
            rs += __shfl_xor(rs, 32);
            if (noresc) {
                l_i += rs;
            } else {
                float alpha = __expf(m_i - mnew);
                l_i = l_i * alpha + rs;
                m_i = mnew;
                // redistribute alpha to O rows (row query = quad*4+r)
                floatx4 av;
#pragma unroll
                for (int r = 0; r < 4; ++r) av[r] = __shfl(alpha, quad * 4 + r);
#pragma unroll
                for (int dt = 0; dt < 16; ++dt) oacc[dt] *= av;
            }

            // ---- O += P V : A = P (own wave's LDS), B = sV rows ----
            __builtin_amdgcn_s_setprio(1);
#pragma unroll
            for (int k2 = 0; k2 < 2; ++k2) {
                bf16x8 pf = *(const bf16x8*)(sP + tl * 72 + k2 * 32 + quad * 8);
#pragma unroll
                for (int dt = 0; dt < 16; ++dt) {
                    int d = dt * 16 + tl;
                    int ph = (k2 * 4 + quad) ^ (d & 7);
                    bf16x8 vf = *(const bf16x8*)(sV + d * 64 + ph * 8);
                    oacc[dt] = __builtin_amdgcn_mfma_f32_16x16x32_bf16(pf, vf, oacc[dt], 0, 0, 0);
                }
            }
            __builtin_amdgcn_s_setprio(0);
            __syncthreads();  // all waves done with sK/sV/sP before next drain
        }

        // ---- epilogue: normalized partial O + (m,l) ----
        floatx4 inv;
#pragma unroll
        for (int r = 0; r < 4; ++r) {
            float lv = __shfl(l_i, quad * 4 + r);
            inv[r] = (lv > 0.f) ? 1.0f / lv : 0.f;
        }
#pragma unroll
        for (int dt = 0; dt < 16; ++dt) {
#pragma unroll
            for (int r = 0; r < 4; ++r) {
                long long row = qr0 + w * 16 + quad * 4 + r;
                Op[row * HID + h * HDIM + dt * 16 + tl] = (bf16_t)(oacc[dt][r] * inv[r]);
            }
        }
        if (quad == 0) {
            long long mi = ((long long)(kh * NHEADS + h) * S_LEN + qr0 + w * 16 + tl) * 2;
            mlb[mi] = m_i;
            mlb[mi + 1] = l_i;
        }
    }
}

// ---------------- combine the two k-half partials (in-place over op0) ----------------
__global__ __launch_bounds__(256) void combine_kernel(bf16_t* __restrict__ op0,
                                                      const bf16_t* __restrict__ op1,
                                                      const float* __restrict__ mlb) {
    int h = blockIdx.x;
    int row = blockIdx.y;
    int d = threadIdx.x;
    long long m0i = ((long long)h * S_LEN + row) * 2;
    long long m1i = ((long long)(NHEADS + h) * S_LEN + row) * 2;
    float m0 = mlb[m0i], l0 = mlb[m0i + 1];
    float m1 = mlb[m1i], l1 = mlb[m1i + 1];
    float M = fmaxf(m0, m1);
    float w0 = (l0 > 0.f) ? l0 * __expf(m0 - M) : 0.f;
    float w1 = (l1 > 0.f) ? l1 * __expf(m1 - M) : 0.f;
    float inv = 1.0f / (w0 + w1);
    long long idx = (long long)row * HID + h * HDIM + d;
    float v = (w0 * (float)op0[idx] + w1 * (float)op1[idx]) * inv;
    op0[idx] = (bf16_t)v;
}

// ---------------- MFMA GEMM: C[M,N] = A[M,K] * Bt[N,K]^T ----------------
// BM x 256 tile (BM = 256 or 128), BK=64, 512 threads = 8 waves (2Mx4N, per-wave
// (BM/2) x 64 output). Double-buffered LDS (128/96 KiB, 1 block/CU).
// Sync skeleton identical to proven R2 ordering: [stage(t+1) issue] ->
// [counted vmcnt retires only tile t's loads] -> [raw s_barrier] -> [4-phase
// compute] -> [lgkmcnt(0)] -> [raw s_barrier]. Issue-to-wait gap = one full
// 256-wide K-tile of compute (covers L3/HBM latency). Phase-split compute
// (quadrants (0,0)->(0,1)->(1,1)->(1,0), A/B frags reused across neighbors)
// bounds register liveness and gives setprio a role-split to arbitrate (T5).
// MODE: 0 = bf16 store; 1 = fp32 store of resid+acc; 2 = bf16 store of
// gelu(aux)*acc (aux bf16, may alias C).
template <int BM, int MODE>
__global__ __launch_bounds__(512) void gemm256_kernel(const bf16_t* __restrict__ A, int lda,
                                                      const bf16_t* __restrict__ Bt, int ldb,
                                                      void* __restrict__ Cv, int ldc,
                                                      const void* __restrict__ aux, int K) {
    constexpr int LPT = BM / 64 + 4;              // gload_lds per thread per K-tile (8 or 6)
    constexpr int WAIT_VM_LPT = 0x0f70 | LPT;     // vmcnt(LPT)
    constexpr int MF = BM / 32;                   // m-frags per wave (8 or 4)
    __shared__ bf16_t smem[2][(BM + 256) * 64];   // [buf][A(BMx64) | B(256x64)]

    const int tid = threadIdx.x;
    const int n0 = blockIdx.x * 256;
    const int m0 = blockIdx.y * BM;
    const int lane = tid & 63;
    const int wid = tid >> 6;                     // 0..7
    const int wm = (wid >> 2) * (BM / 2);         // 2 M-halves
    const int wn = (wid & 3) * 64;                // 4 N-quarters
    const int tl = lane & 15;
    const int quad = lane >> 4;

    floatx4 acc[MF][4] = {};

    // stage one BMx64 A-tile + 256x64 B-tile into smem[buf]
    // rows are 128 B = 8 chunks of 16 B, XOR chunk swizzle g = sg ^ (m&7)
    auto stage = [&](int buf, int k0) {
        bf16_t* sA = smem[buf];
        bf16_t* sB = smem[buf] + BM * 64;
#pragma unroll
        for (int it = 0; it < BM / 64; ++it) {
            int s = it * 512 + tid;
            int m = s >> 3, sg = s & 7, g = sg ^ (m & 7);
            const bf16_t* ga = A + (long long)(m0 + m) * lda + k0 + g * 8;
            __builtin_amdgcn_global_load_lds((const __attribute__((address_space(1))) void*)ga,
                                             (__attribute__((address_space(3))) void*)(sA + s * 8),
                                             16, 0, 0);
        }
#pragma unroll
        for (int it = 0; it < 4; ++it) {
            int s = it * 512 + tid;
            int m = s >> 3, sg = s & 7, g = sg ^ (m & 7);
            const bf16_t* gb = Bt + (long long)(n0 + m) * ldb + k0 + g * 8;
            __builtin_amdgcn_global_load_lds((const __attribute__((address_space(1))) void*)gb,
                                             (__attribute__((address_space(3))) void*)(sB + s * 8),
                                             16, 0, 0);
        }
    };

    const int nk = K >> 6;
    stage(0, 0);
    int cur = 0;

    for (int t = 0; t < nk; ++t) {
        if (t + 1 < nk) {
            stage(cur ^ 1, (t + 1) * 64);                 // next tile: stays in flight all iter
            __builtin_amdgcn_s_waitcnt(WAIT_VM_LPT);      // retire only tile t's loads
        } else {
            __builtin_amdgcn_s_waitcnt(WAITCNT_VM0);      // last tile: drain
        }
        __builtin_amdgcn_s_barrier();                     // raw: prefetch uninterrupted
        __builtin_amdgcn_sched_barrier(0);

        const bf16_t* sA = smem[cur];
        const bf16_t* sB = smem[cur] + BM * 64;

        if constexpr (BM == 256) {
            bf16x8 a[4][2], b0[2][2], b1[2][2];
            // ---- phase 0: load A(mh=0) + B(nh=0); MFMA quadrant (0,0)
#pragma unroll
            for (int mi = 0; mi < 4; ++mi) {
                int m = wm + mi * 16 + tl;
#pragma unroll
                for (int kk = 0; kk < 2; ++kk) {
                    int sg = (kk * 4 + quad) ^ (m & 7);
                    a[mi][kk] = *(const bf16x8*)(sA + m * 64 + sg * 8);
                }
            }
#pragma unroll
            for (int ni = 0; ni < 2; ++ni) {
                int n = wn + ni * 16 + tl;
#pragma unroll
                for (int kk = 0; kk < 2; ++kk) {
                    int sg = (kk * 4 + quad) ^ (n & 7);
                    b0[ni][kk] = *(const bf16x8*)(sB + n * 64 + sg * 8);
                }
            }
            __builtin_amdgcn_s_setprio(1);
#pragma unroll
            for (int mi = 0; mi < 4; ++mi)
#pragma unroll
                for (int ni = 0; ni < 2; ++ni)
#pragma unroll
                    for (int kk = 0; kk < 2; ++kk)
                        acc[mi][ni] = __builtin_amdgcn_mfma_f32_16x16x32_bf16(a[mi][kk], b0[ni][kk], acc[mi][ni], 0, 0, 0);
            __builtin_amdgcn_s_setprio(0);
            __builtin_amdgcn_sched_barrier(0);
            // ---- phase 1: load B(nh=1); MFMA quadrant (0,1)
#pragma unroll
            for (int ni = 0; ni < 2; ++ni) {
                int n = wn + 32 + ni * 16 + tl;
#pragma unroll
                for (int kk = 0; kk < 2; ++kk) {
                    int sg = (kk * 4 + quad) ^ (n & 7);
                    b1[ni][kk] = *(const bf16x8*)(sB + n * 64 + sg * 8);
                }
            }
            __builtin_amdgcn_s_setprio(1);
#pragma unroll
            for (int mi = 0; mi < 4; ++mi)
#pragma unroll
                for (int ni = 0; ni < 2; ++ni)
#pragma unroll
                    for (int kk = 0; kk < 2; ++kk)
                        acc[mi][2 + ni] = __builtin_amdgcn_mfma_f32_16x16x32_bf16(a[mi][kk], b1[ni][kk], acc[mi][2 + ni], 0, 0, 0);
            __builtin_amdgcn_s_setprio(0);
            __builtin_amdgcn_sched_barrier(0);
            // ---- phase 2: load A(mh=1); MFMA quadrant (1,1)
#pragma unroll
            for (int mi = 0; mi < 4; ++mi) {
                int m = wm + 64 + mi * 16 + tl;
#pragma unroll
                for (int kk = 0; kk < 2; ++kk) {
                    int sg = (kk * 4 + quad) ^ (m & 7);
                    a[mi][kk] = *(const bf16x8*)(sA + m * 64 + sg * 8);
                }
            }
            __builtin_amdgcn_s_setprio(1);
#pragma unroll
            for (int mi = 0; mi < 4; ++mi)
#pragma unroll
                for (int ni = 0; ni < 2; ++ni)
#pragma unroll
                    for (int kk = 0; kk < 2; ++kk)
                        acc[4 + mi][2 + ni] = __builtin_amdgcn_mfma_f32_16x16x32_bf16(a[mi][kk], b1[ni][kk], acc[4 + mi][2 + ni], 0, 0, 0);
            __builtin_amdgcn_s_setprio(0);
            __builtin_amdgcn_sched_barrier(0);
            // ---- phase 3: MFMA quadrant (1,0) (reuses a, b0)
            __builtin_amdgcn_s_setprio(1);
#pragma unroll
            for (int mi = 0; mi < 4; ++mi)
#pragma unroll
                for (int ni = 0; ni < 2; ++ni)
#pragma unroll
                    for (int kk = 0; kk < 2; ++kk)
                        acc[4 + mi][ni] = __builtin_amdgcn_mfma_f32_16x16x32_bf16(a[mi][kk], b0[ni][kk], acc[4 + mi][ni], 0, 0, 0);
            __builtin_amdgcn_s_setprio(0);
        } else {
            // BM == 128: per-wave 64x64, A loaded once, 4 phases over n-frags
            bf16x8 a[4][2];
#pragma unroll
            for (int mi = 0; mi < 4; ++mi) {
                int m = wm + mi * 16 + tl;
#pragma unroll
                for (int kk = 0; kk < 2; ++kk) {
                    int sg = (kk * 4 + quad) ^ (m & 7);
                    a[mi][kk] = *(const bf16x8*)(sA + m * 64 + sg * 8);
                }
            }
            __builtin_amdgcn_sched_barrier(0);
#pragma unroll
            for (int nh = 0; nh < 4; ++nh) {
                bf16x8 b[2];
                int n = wn + nh * 16 + tl;
#pragma unroll
                for (int kk = 0; kk < 2; ++kk) {
                    int sg = (kk * 4 + quad) ^ (n & 7);
                    b[kk] = *(const bf16x8*)(sB + n * 64 + sg * 8);
                }
                __builtin_amdgcn_s_setprio(1);
#pragma unroll
                for (int mi = 0; mi < 4; ++mi)
#pragma unroll
                    for (int kk = 0; kk < 2; ++kk)
                        acc[mi][nh] = __builtin_amdgcn_mfma_f32_16x16x32_bf16(a[mi][kk], b[kk], acc[mi][nh], 0, 0, 0);
                __builtin_amdgcn_s_setprio(0);
                __builtin_amdgcn_sched_barrier(0);
            }
        }

        __builtin_amdgcn_s_waitcnt(WAITCNT_LGKM0);        // all reads of buf cur done
        __builtin_amdgcn_sched_barrier(0);
        __builtin_amdgcn_s_barrier();                     // raw: cur may be overwritten next iter
        cur ^= 1;
    }

    // epilogue: C/D layout col=lane&15, row=quad*4+r
#pragma unroll
    for (int f = 0; f < MF; ++f) {
        int moff = (BM == 256) ? ((f >> 2) * 64 + (f & 3) * 16) : (f * 16);
#pragma unroll
        for (int j = 0; j < 4; ++j) {
#pragma unroll
            for (int r = 0; r < 4; ++r) {
                int gr = m0 + wm + moff + quad * 4 + r;
                int gc = n0 + wn + j * 16 + tl;
                long long idx = (long long)gr * ldc + gc;
                float v = acc[f][j][r];
                if (MODE == 0) {
                    ((bf16_t*)Cv)[idx] = (bf16_t)v;
                } else if (MODE == 1) {
                    ((float*)Cv)[idx] = ((const float*)aux)[idx] + v;
                } else {
                    float g = (float)((const bf16_t*)aux)[idx];
                    float t = 0.7978845608028654f * (g + 0.044715f * g * g * g);
                    float ge = 0.5f * g * (1.0f + tanhf(t));
                    ((bf16_t*)Cv)[idx] = (bf16_t)(ge * v);
                }
            }
        }
    }
}

// ---------------- launch ----------------
extern "C" void kernel_launch(void* const* d_in, const int* in_sizes, int n_in,
                              void* d_out, int out_size, void* d_ws, size_t ws_size,
                              hipStream_t stream) {
    const float* hidden = (const float*)d_in[0];
    const float* q_w    = (const float*)d_in[1];
    const float* k_w    = (const float*)d_in[2];
    const float* v_w    = (const float*)d_in[3];
    const float* o_w    = (const float*)d_in[4];
    const float* gate_w = (const float*)d_in[5];
    const float* up_w   = (const float*)d_in[6];
    const float* down_w = (const float*)d_in[7];
    const float* ln1_w  = (const float*)d_in[8];
    const float* ln2_w  = (const float*)d_in[9];
    const int* amask    = (const int*)d_in[10];
    const int* pos_ids  = (const int*)d_in[11];
    float* out = (float*)d_out;

    // ---- workspace layout (peak 200 MiB) ----
    const size_t MB = 1ull << 20;
    char* ws = (char*)d_ws;
    bf16_t* wqT = (bf16_t*)(ws + 0 * MB);     // rows 0..2047 of fused wqkvT
    bf16_t* wkT = (bf16_t*)(ws + 8 * MB);     // rows 2048..3071
    bf16_t* wvT = (bf16_t*)(ws + 12 * MB);    // rows 3072..4095
    bf16_t* woT = (bf16_t*)(ws + 16 * MB);
    bf16_t* wgT = (bf16_t*)(ws + 24 * MB);
    bf16_t* wuT = (bf16_t*)(ws + 56 * MB);
    bf16_t* wdT = (bf16_t*)(ws + 88 * MB);
    bf16_t* xb    = (bf16_t*)(ws + 120 * MB);  // rms1 out; later op0/attnb/xb2
    bf16_t* qkvb  = (bf16_t*)(ws + 136 * MB);  // fused [4096][4096]
    bf16_t* vT    = (bf16_t*)(ws + 168 * MB);
    bf16_t* op0   = (bf16_t*)(ws + 120 * MB);  // aliases xb (dead during attention)
    bf16_t* op1   = (bf16_t*)(ws + 176 * MB);
    float*  mlb   = (float*) (ws + 192 * MB);
    bf16_t* attnb = (bf16_t*)(ws + 120 * MB);  // combine output, in-place over op0
    bf16_t* xb2   = (bf16_t*)(ws + 120 * MB);  // rms2 out, over dead attnb
    bf16_t* gateb = (bf16_t*)(ws + 136 * MB);  // 64 MiB, over dead attention pool
    (void)ws_size; (void)in_sizes; (void)n_in; (void)out_size;

    dim3 blk(256);
    dim3 blkG(512);

    // weight transpose + bf16 cast: w[K,N] -> wT[N,K]
    transpose_bf16_kernel<float><<<dim3(64, 64), blk, 0, stream>>>(q_w, wqT, 2048, 2048);
    transpose_bf16_kernel<float><<<dim3(32, 64), blk, 0, stream>>>(k_w, wkT, 1024, 2048);
    transpose_bf16_kernel<float><<<dim3(32, 64), blk, 0, stream>>>(v_w, wvT, 1024, 2048);
    transpose_bf16_kernel<float><<<dim3(64, 64), blk, 0, stream>>>(o_w, woT, 2048, 2048);
    transpose_bf16_kernel<float><<<dim3(256, 64), blk, 0, stream>>>(gate_w, wgT, 8192, 2048);
    transpose_bf16_kernel<float><<<dim3(256, 64), blk, 0, stream>>>(up_w, wuT, 8192, 2048);
    transpose_bf16_kernel<float><<<dim3(64, 256), blk, 0, stream>>>(down_w, wdT, 2048, 8192);

    // RMSNorm 1
    rmsnorm_kernel<<<dim3(S_LEN), blk, 0, stream>>>(hidden, ln1_w, xb);

    // fused QKV projection: [4096,2048] x [4096,2048]^T -> qkv [4096][4096]
    gemm256_kernel<256, 0><<<dim3(16, 16), blkG, 0, stream>>>(xb, HID, wqT, HID, qkvb, QKV_LD, nullptr, HID);

    // RoPE (in-place on fused qkv)
    rope_kernel<<<dim3(S_LEN), blk, 0, stream>>>(qkvb, pos_ids);

    // v^T for flash PV: v region of qkv (cols 3072..4095, stride 4096) -> vT[1024][4096]
    transpose_bf16_kernel<bf16_t><<<dim3(32, 128), blk, 0, stream>>>(qkvb + 3072, vT, QKV_LD, S_LEN);

    // flash attention (split-K halves, paired q-tiles) -> op0/op1 + ml
    flash_attn_kernel<<<dim3(32, NHEADS, 2), blk, 0, stream>>>(qkvb, vT, op0, op1, mlb, amask);
    combine_kernel<<<dim3(NHEADS, S_LEN), blk, 0, stream>>>(op0, op1, mlb);

    // O projection + residual into d_out (fp32): N=2048 -> BM=128 variant
    gemm256_kernel<128, 1><<<dim3(8, 32), blkG, 0, stream>>>(attnb, 2048, woT, 2048, out, 2048, hidden, 2048);

    // RMSNorm 2
    rmsnorm_kernel<<<dim3(S_LEN), blk, 0, stream>>>(out, ln2_w, xb2);

    // MLP: gate, up (fused gelu*up in-place), down (+residual into d_out)
    gemm256_kernel<256, 0><<<dim3(32, 16), blkG, 0, stream>>>(xb2, HID, wgT, HID, gateb, FFN, nullptr, HID);
    gemm256_kernel<256, 2><<<dim3(32, 16), blkG, 0, stream>>>(xb2, HID, wuT, HID, gateb, FFN, gateb, HID);
    gemm256_kernel<128, 1><<<dim3(8, 32), blkG, 0, stream>>>(gateb, FFN, wdT, FFN, out, 2048, out, FFN);
}